// Round 4
// baseline (512.321 us; speedup 1.0000x reference)
//
#include <hip/hip_runtime.h>
#include <hip/hip_bf16.h>

// ---- problem constants ----
#define BATCH 4
#define SEQ   2048
#define DIN   4096
#define DOUT  4096
#define MTOT  (BATCH * SEQ)     // 8192
#define RANK  16

typedef __bf16 bf8_t  __attribute__((ext_vector_type(8)));
typedef float  f4_t   __attribute__((ext_vector_type(4)));

#define GLD_LDS(g, l) \
  __builtin_amdgcn_global_load_lds((const __attribute__((address_space(1))) void*)(g), \
                                   (__attribute__((address_space(3))) void*)(l), 16, 0, 0)

// ---------------------------------------------------------------------------
// Pre-kernel: ONE launch does all of:
//   blocks [0, 512):    lowS = scale * (x @ A[b]^T)  (no atomics, full-K per
//                       block, 4 waves = k-quarters, LDS reduce) + emit xb bf16
//   blocks [512, 2048): grid-stride f32->bf16 convert of W
// ---------------------------------------------------------------------------
#define LOWBLK 512
#define PREGRID 2048

__global__ __launch_bounds__(256) void pre_kernel(
    const float* __restrict__ x, const float* __restrict__ w,
    const float* __restrict__ Aw, const float* __restrict__ scales,
    const int* __restrict__ adapter_id,
    __bf16* __restrict__ xb, __bf16* __restrict__ wb,
    float* __restrict__ lowS) {
  const int bid = blockIdx.x;
  if (bid < LOWBLK) {
    __shared__ float red[4][16][16];
    const int t    = threadIdx.x;
    const int wv   = t >> 6;
    const int lane = t & 63;
    const int quad = lane >> 4;
    const int l16  = lane & 15;
    const int m0   = bid * 16;
    const int b    = adapter_id[m0 >> 11];
    const int kb   = wv * 1024;   // wave k-quarter

    const float*  xp  = x  + (size_t)(m0 + l16) * DIN + kb + quad * 8;
    __bf16*       xbp = xb + (size_t)(m0 + l16) * DIN + kb + quad * 8;
    const float*  ap  = Aw + ((size_t)b * RANK + l16) * DIN + kb + quad * 8;

    f4_t acc = (f4_t)0.f;
#pragma unroll 4
    for (int it = 0; it < 32; ++it) {
      const int off = it * 32;
      f4_t u0 = *(const f4_t*)(xp + off);
      f4_t u1 = *(const f4_t*)(xp + off + 4);
      f4_t v0 = *(const f4_t*)(ap + off);
      f4_t v1 = *(const f4_t*)(ap + off + 4);
      bf8_t af, bfr;
#pragma unroll
      for (int e = 0; e < 4; ++e) {
        af[e] = (__bf16)u0[e]; af[4 + e] = (__bf16)u1[e];
        bfr[e] = (__bf16)v0[e]; bfr[4 + e] = (__bf16)v1[e];
      }
      *(bf8_t*)(xbp + off) = af;   // fused x f32->bf16 emission
      acc = __builtin_amdgcn_mfma_f32_16x16x32_bf16(af, bfr, acc, 0, 0, 0);
    }
    // C/D layout: col(rank) = l16, row = quad*4 + e
#pragma unroll
    for (int e = 0; e < 4; ++e) red[wv][quad * 4 + e][l16] = acc[e];
    __syncthreads();
    const int r = t >> 4, c = t & 15;
    const float s = red[0][r][c] + red[1][r][c] + red[2][r][c] + red[3][r][c];
    lowS[(size_t)(m0 + r) * RANK + c] = s * scales[b];
  } else {
    // W conversion: 8192 chunks of 256 threads x 8 elems, grid-stride
    for (int cb = bid - LOWBLK; cb < 8192; cb += PREGRID - LOWBLK) {
      const size_t i = ((size_t)cb * 256 + threadIdx.x) * 8;
      f4_t a = *(const f4_t*)(w + i);
      f4_t bb = *(const f4_t*)(w + i + 4);
      bf8_t o;
#pragma unroll
      for (int e = 0; e < 4; ++e) { o[e] = (__bf16)a[e]; o[4 + e] = (__bf16)bb[e]; }
      *(bf8_t*)(wb + i) = o;
    }
  }
}

// ---------------------------------------------------------------------------
// GEMM: out = x @ W^T + bias + lowS @ loraB[b]^T   (bf16, f32 out)
// 256x256 tile, BK=64, 8 waves (2M x 4N), 8-phase schedule.
// RACE-FIXED rotation: stage granularity matches ACTUAL last-read phases
// (every phase's LDA/LDB is executed by waves of BOTH halves):
//   buf A rows 0-63  ("Alow",  2 glds) last read P1 -> restage P2
//   buf A rows 64-127("Ahigh", 2 glds) last read P3 -> restage P4
//   buf B (both halves)                last read P4 -> restage P5/P6
// Rotation: buf0(t+2) @ P2/P4/P5/P6; buf1(t+3) @ P6/P8/nextP1/nextP2.
// Counted VMW(4) at P4 & P8 only, each followed by its barrier BEFORE the
// dependent reads (cross-wave confirm), each confirming exactly the next
// tile's 4 stage-units while leaving 4 newer loads in flight.
// ---------------------------------------------------------------------------
#define BM 256
#define BN 256
#define BKT 64
#define NT (DIN / BKT)   // 64 K-tiles
#define NIT (NT / 2)     // 32 iterations x 2 tiles

#define BAR() __builtin_amdgcn_s_barrier()
#define VMW(n) asm volatile("s_waitcnt vmcnt(" #n ")" ::: "memory")

__global__ __launch_bounds__(512, 2) void lora_gemm_kernel(
    const __bf16* __restrict__ x, const __bf16* __restrict__ wgt,
    const float* __restrict__ bias, const float* __restrict__ loraB,
    const int* __restrict__ adapter_id, const float* __restrict__ lowS,
    float* __restrict__ out) {
  __shared__ __bf16 lds[2][2][2][128 * 64];  // [buf][A/B][half][128 rows x 64 k]

  const int t    = threadIdx.x;
  const int w    = t >> 6;
  const int lane = t & 63;
  const int quad = lane >> 4;
  const int l16  = lane & 15;
  const int wm   = w >> 2;        // 0..1 : 128-row band
  const int wn   = w & 3;         // 0..3 : 64-col band

  // XCD-aware bijective swizzle: 512 blocks, 8 XCDs, 64 blocks/XCD contiguous.
  const int linear = blockIdx.y * 16 + blockIdx.x;      // gridDim.x == 16
  const int swz = (linear & 7) * 64 + (linear >> 3);
  const int m0 = (swz >> 4) * BM;
  const int n0 = (swz & 15) * BN;

  // staging: thread t covers row t>>3, LDS chunk t&7; source chunk is
  // inverse-swizzled sc = (t&7) ^ ((row>>1)&7) so reads are conflict-free.
  const int srow = t >> 3;
  const int sc   = (t & 7) ^ ((t >> 4) & 7);
  const __bf16* gA = x   + (size_t)(m0 + srow) * DIN + sc * 8;
  const __bf16* gB = wgt + (size_t)(n0 + srow) * DIN + sc * 8;
  const int ldsw = w * 512;       // wave-uniform elem offset; HW adds lane*16B

  // Stage units: each = 2 x global_load_lds of 64 rows (4096 elems).
#define STG_A_LOW(buf, kel) do {                                                 \
    GLD_LDS(gA + (kel),                       &lds[buf][0][0][ldsw]);            \
    GLD_LDS(gA + (size_t)128 * DIN + (kel),   &lds[buf][0][1][ldsw]);            \
  } while (0)
#define STG_A_HIGH(buf, kel) do {                                                \
    GLD_LDS(gA + (size_t)64 * DIN + (kel),    &lds[buf][0][0][4096 + ldsw]);     \
    GLD_LDS(gA + (size_t)192 * DIN + (kel),   &lds[buf][0][1][4096 + ldsw]);     \
  } while (0)
#define STG_B(buf, half, kel) do {                                               \
    GLD_LDS(gB + (size_t)((half) * 128) * DIN + (kel),                           \
            &lds[buf][1][half][ldsw]);                                           \
    GLD_LDS(gB + (size_t)((half) * 128 + 64) * DIN + (kel),                      \
            &lds[buf][1][half][4096 + ldsw]);                                    \
  } while (0)

  // fragment-read offsets: stored chunk = (ks*4+quad) ^ ((l16>>1)&7)
  const int st0 = (quad ^ ((l16 >> 1) & 7)) * 8;
  const int st1 = ((4 + quad) ^ ((l16 >> 1) & 7)) * 8;

  bf8_t a[4][2], b[2][2];
  f4_t acc[8][4];
#pragma unroll
  for (int i = 0; i < 8; ++i)
#pragma unroll
    for (int j = 0; j < 4; ++j) acc[i][j] = (f4_t)0.f;

#define LDA(buf, mh) do {                                                        \
    const __bf16* base_ = &lds[buf][0][wm][0];                                   \
    _Pragma("unroll")                                                            \
    for (int mq = 0; mq < 4; ++mq) {                                             \
      const int r_ = ((mh) * 4 + mq) * 16 + l16;                                 \
      a[mq][0] = *(const bf8_t*)(base_ + r_ * 64 + st0);                         \
      a[mq][1] = *(const bf8_t*)(base_ + r_ * 64 + st1);                         \
    }                                                                            \
  } while (0)

#define LDB(buf, nh) do {                                                        \
    const __bf16* base_ = &lds[buf][1][wn >> 1][(wn & 1) * 4096];                \
    _Pragma("unroll")                                                            \
    for (int nq = 0; nq < 2; ++nq) {                                             \
      const int r_ = ((nh) * 2 + nq) * 16 + l16;                                 \
      b[nq][0] = *(const bf8_t*)(base_ + r_ * 64 + st0);                         \
      b[nq][1] = *(const bf8_t*)(base_ + r_ * 64 + st1);                         \
    }                                                                            \
  } while (0)

#define MM(mh, nh) do {                                                          \
    __builtin_amdgcn_s_setprio(1);                                               \
    _Pragma("unroll")                                                            \
    for (int ks = 0; ks < 2; ++ks)                                               \
      _Pragma("unroll")                                                          \
      for (int mq = 0; mq < 4; ++mq)                                             \
        _Pragma("unroll")                                                        \
        for (int nq = 0; nq < 2; ++nq)                                           \
          acc[(mh) * 4 + mq][(nh) * 2 + nq] = __builtin_amdgcn_mfma_f32_16x16x32_bf16( \
              a[mq][ks], b[nq][ks], acc[(mh) * 4 + mq][(nh) * 2 + nq], 0, 0, 0); \
    __builtin_amdgcn_s_setprio(0);                                               \
  } while (0)

  // ---- prologue: buf0 = tile0 complete (8 glds), then buf1.A of tile1
  //      (4 glds, mimicking steady-state P6/P8 issues). VMW(4) confirms
  //      buf0's 8, leaves buf1.A's 4 in flight; barrier makes it cross-wave.
  STG_A_LOW(0, 0); STG_A_HIGH(0, 0); STG_B(0, 0, 0); STG_B(0, 1, 0);
  STG_A_LOW(1, BKT); STG_A_HIGH(1, BKT);
  VMW(4);
  BAR();

  // ---- 8-phase main loop (2 K-tiles / iter) ------------------------------
  for (int it = 0; it < NIT; ++it) {
    const int k1 = (2 * it + 1) * BKT;
    const int k2 = ((2 * it + 2) & (NT - 1)) * BKT;   // wrap: garbage, never read
    const int k3 = ((2 * it + 3) & (NT - 1)) * BKT;
    // P1: quadrant (0,0) of tile t (buf0); stage buf1.Bh0 (tile t+1)
    LDA(0, 0); LDB(0, 0); STG_B(1, 0, k1);
    BAR(); MM(0, 0); BAR();
    // P2: (0,1); stage buf1.Bh1 (t+1) then buf0.Alow (t+2; Alow last read P1)
    LDB(0, 1); STG_B(1, 1, k1); STG_A_LOW(0, k2);
    BAR(); MM(0, 1); BAR();
    // P3: (1,1); no stage
    LDA(0, 1);
    BAR(); MM(1, 1); BAR();
    // P4: (1,0); stage buf0.Ahigh (t+2; Ahigh last read P3).
    //     VMW(4): confirms {buf1.Alow(prev P6), buf1.Ahigh(prev P8),
    //     buf1.Bh0(P1), buf1.Bh1(P2)} = tile t+1 complete; leaves
    //     {buf0.Alow(P2), buf0.Ahigh(P4)} in flight. Barrier -> P5 reads.
    LDB(0, 0); STG_A_HIGH(0, k2);
    VMW(4);
    BAR(); MM(1, 0); BAR();
    // P5: quadrant (0,0) of tile t+1 (buf1); stage buf0.Bh0 (t+2; B last read P4)
    LDA(1, 0); LDB(1, 0); STG_B(0, 0, k2);
    BAR(); MM(0, 0); BAR();
    // P6: (0,1); stage buf0.Bh1 (t+2) then buf1.Alow (t+3; Alow last read P5)
    LDB(1, 1); STG_B(0, 1, k2); STG_A_LOW(1, k3);
    BAR(); MM(0, 1); BAR();
    // P7: (1,1); no stage
    LDA(1, 1);
    BAR(); MM(1, 1); BAR();
    // P8: (1,0); stage buf1.Ahigh (t+3; Ahigh last read P7).
    //     VMW(4): confirms {buf0.Alow(P2), buf0.Ahigh(P4), buf0.Bh0(P5),
    //     buf0.Bh1(P6)} = tile t+2 complete; leaves {buf1.Alow(P6),
    //     buf1.Ahigh(P8)} in flight. Barrier -> next P1 reads buf0.
    LDB(1, 0); STG_A_HIGH(1, k3);
    VMW(4);
    BAR(); MM(1, 0); BAR();
  }
#undef STG_A_LOW
#undef STG_A_HIGH
#undef STG_B
#undef LDA
#undef LDB
#undef MM

  // ---- LoRA epilogue: one zero-padded MFMA k-step (k=0..15 valid) --------
  const int b_id = adapter_id[m0 >> 11];
  bf8_t alow[8], blow[4];
  if (quad < 2) {
#pragma unroll
    for (int mf = 0; mf < 8; ++mf) {
      const float* p = &lowS[(size_t)(m0 + wm * 128 + mf * 16 + l16) * RANK + quad * 8];
      f4_t u0 = *(const f4_t*)p;
      f4_t u1 = *(const f4_t*)(p + 4);
#pragma unroll
      for (int e = 0; e < 4; ++e) { alow[mf][e] = (__bf16)u0[e]; alow[mf][4 + e] = (__bf16)u1[e]; }
    }
#pragma unroll
    for (int nf = 0; nf < 4; ++nf) {
      const float* p = &loraB[((size_t)b_id * DOUT + n0 + wn * 64 + nf * 16 + l16) * RANK + quad * 8];
      f4_t u0 = *(const f4_t*)p;
      f4_t u1 = *(const f4_t*)(p + 4);
#pragma unroll
      for (int e = 0; e < 4; ++e) { blow[nf][e] = (__bf16)u0[e]; blow[nf][4 + e] = (__bf16)u1[e]; }
    }
  } else {
#pragma unroll
    for (int i = 0; i < 8; ++i)
#pragma unroll
      for (int e = 0; e < 8; ++e) alow[i][e] = (__bf16)0.f;
#pragma unroll
    for (int j = 0; j < 4; ++j)
#pragma unroll
      for (int e = 0; e < 8; ++e) blow[j][e] = (__bf16)0.f;
  }
#pragma unroll
  for (int mf = 0; mf < 8; ++mf)
#pragma unroll
    for (int nf = 0; nf < 4; ++nf)
      acc[mf][nf] = __builtin_amdgcn_mfma_f32_16x16x32_bf16(alow[mf], blow[nf], acc[mf][nf], 0, 0, 0);

  // ---- bias + store (C/D layout: col = lane&15, row = quad*4 + reg) ------
#pragma unroll
  for (int nf = 0; nf < 4; ++nf) {
    const int c = n0 + wn * 64 + nf * 16 + l16;
    const float bc = bias[c];
#pragma unroll
    for (int mf = 0; mf < 8; ++mf) {
      const int r0 = m0 + wm * 128 + mf * 16 + quad * 4;
#pragma unroll
      for (int e = 0; e < 4; ++e)
        out[(size_t)(r0 + e) * DOUT + c] = acc[mf][nf][e] + bc;
    }
  }
}

extern "C" void kernel_launch(void* const* d_in, const int* in_sizes, int n_in,
                              void* d_out, int out_size, void* d_ws, size_t ws_size,
                              hipStream_t stream) {
  const float* x       = (const float*)d_in[0];
  const float* weight  = (const float*)d_in[1];
  const float* bias    = (const float*)d_in[2];
  const float* lora_a  = (const float*)d_in[3];
  const float* lora_b  = (const float*)d_in[4];
  const float* scaling = (const float*)d_in[5];
  const int*   adapter = (const int*)d_in[6];
  float* out = (float*)d_out;

  // workspace layout: x_bf16 (64 MiB) | W_bf16 (32 MiB) | lowS (512 KiB)
  __bf16* xb   = (__bf16*)d_ws;
  __bf16* wb   = xb + (size_t)MTOT * DIN;
  float*  lowS = (float*)(wb + (size_t)DOUT * DIN);

  pre_kernel<<<PREGRID, 256, 0, stream>>>(x, weight, lora_a, scaling, adapter,
                                          xb, wb, lowS);
  dim3 grid(DOUT / BN, MTOT / BM);
  lora_gemm_kernel<<<grid, 512, 0, stream>>>(xb, wb, bias, lora_b, adapter, lowS, out);
}